// Round 5
// baseline (187.695 us; speedup 1.0000x reference)
//
#include <hip/hip_runtime.h>
#include <math.h>

// Problem sizes (fixed by the reference)
#define B   4
#define TQ  256
#define TV  1024
#define D   512
#define A   128

#define LOG2E     1.4426950408889634f
#define TWO_LOG2E 2.8853900817779268f
#define NEG_BIG_F (-1e9f)

#define QBLK (B * TQ / 8)   // 128 q-projection blocks
#define KBLK (B * TV / 8)   // 512 k-projection blocks

// ---------------------------------------------------------------------------
// Fused projection + exp(2x) for BOTH q and k. Also zero-fills d_out for the
// pv kernel's atomics (stream-ordered, runs first).
//   q path: Eq[r, a]     = exp(2*(ctx[r,:]@Wq[:,a] + bq[a]))   [row-major]
//   k path: EkT[b, a, v] = exp(2*(inp[r,:]@Wk[:,a] + bk[a]))   [TRANSPOSED]
// ---------------------------------------------------------------------------
__global__ __launch_bounds__(512) void proj_exp_kernel(
    const float* __restrict__ ctx, const float* __restrict__ inp,
    const float* __restrict__ Wq, const float* __restrict__ bq,
    const float* __restrict__ Wk, const float* __restrict__ bk,
    float* __restrict__ Eq, float* __restrict__ EkT,
    float* __restrict__ outz) {
  __shared__ float xs[8][D];        // 16 KB
  __shared__ float ps[8][4][A];     // 16 KB (row j, quarter, a)
  __shared__ float es[A][9];        // 4.6 KB (transpose staging, +1 pad)

  // zero d_out: B*TQ*D floats = 131072 float4; grid has 640*512 threads
  {
    size_t gid = (size_t)blockIdx.x * 512 + threadIdx.x;
    if (gid < (size_t)(B * TQ * D / 4))
      ((float4*)outz)[gid] = make_float4(0.f, 0.f, 0.f, 0.f);
  }

  bool isQ = blockIdx.x < QBLK;
  const float* X; const float* W; const float* bias; int r0;
  if (isQ) { X = ctx; W = Wq; bias = bq; r0 = blockIdx.x * 8; }
  else     { X = inp; W = Wk; bias = bk; r0 = (blockIdx.x - QBLK) * 8; }

  // stage 8 rows of X (float4, coalesced)
  {
    const float4* Xv = (const float4*)(X + (size_t)r0 * D);
    float4* xsv = (float4*)&xs[0][0];
    for (int i = threadIdx.x; i < 8 * D / 4; i += 512) xsv[i] = Xv[i];
  }
  __syncthreads();

  int a = threadIdx.x & 127;
  int h = threadIdx.x >> 7;        // 0..3, splits d-range into quarters
  float acc[8];
#pragma unroll
  for (int j = 0; j < 8; ++j) acc[j] = 0.f;

  int dbase = h * (D / 4);
#pragma unroll 2
  for (int dd = 0; dd < D / 4; dd += 4) {
    int d = dbase + dd;
    float w0 = W[(d + 0) * A + a];
    float w1 = W[(d + 1) * A + a];
    float w2 = W[(d + 2) * A + a];
    float w3 = W[(d + 3) * A + a];
#pragma unroll
    for (int j = 0; j < 8; ++j) {
      float4 x = *(const float4*)&xs[j][d];   // wave-uniform addr -> broadcast
      acc[j] = fmaf(x.x, w0, acc[j]);
      acc[j] = fmaf(x.y, w1, acc[j]);
      acc[j] = fmaf(x.z, w2, acc[j]);
      acc[j] = fmaf(x.w, w3, acc[j]);
    }
  }
#pragma unroll
  for (int j = 0; j < 8; ++j) ps[j][h][a] = acc[j];
  __syncthreads();

  float bz = bias[a];
  if (isQ) {
#pragma unroll
    for (int j = h * 2; j < h * 2 + 2; ++j) {
      float t = ((ps[j][0][a] + ps[j][1][a]) + (ps[j][2][a] + ps[j][3][a])) + bz;
      Eq[(size_t)(r0 + j) * A + a] = __builtin_amdgcn_exp2f(t * TWO_LOG2E);
    }
  } else {
#pragma unroll
    for (int j = h * 2; j < h * 2 + 2; ++j) {
      float t = ((ps[j][0][a] + ps[j][1][a]) + (ps[j][2][a] + ps[j][3][a])) + bz;
      es[a][j] = __builtin_amdgcn_exp2f(t * TWO_LOG2E);
    }
    __syncthreads();
    int b  = r0 >> 10;          // TV == 1024
    int v0 = r0 & (TV - 1);
    for (int i = threadIdx.x; i < A * 8; i += 512) {
      int aa = i >> 3, jj = i & 7;
      EkT[((size_t)b * A + aa) * TV + v0 + jj] = es[aa][jj];
    }
  }
}

// ---------------------------------------------------------------------------
// Scores + softmax: TWO q rows per block, 256 threads (4 waves), thread owns
// 4 consecutive v (float4 EkT loads, lane-coalesced 1KB/wave-instr) for BOTH
// rows (8 independent rcp chains). 512 blocks -> 2 blocks/CU.
//   score[v] = sumV - 2 * sum_a v_a / (Eq[a]*EkT[a,v] + 1)
// ---------------------------------------------------------------------------
__global__ __launch_bounds__(256, 8) void score_softmax_kernel(
    const float* __restrict__ Eq, const float* __restrict__ EkT,
    const float* __restrict__ attn_v, const int* __restrict__ mask,
    float* __restrict__ attn) {
  __shared__ float redA[4], redB[4];
  __shared__ float bc[4];

  int tid = threadIdx.x;
  int v0  = (tid & 63) * 4 + (tid >> 6) * 256;  // wave-contiguous float4
  int r0  = blockIdx.x * 2;
  int b   = r0 >> 8;               // TQ == 256

  const float* eqA = Eq + (size_t)r0 * A;
  const float* eqB = eqA + A;

  float sumV = 0.f;
#pragma unroll 16
  for (int i = 0; i < A; ++i) sumV += attn_v[i];

  const float* ekb = EkT + (size_t)b * A * TV + v0;
  float4 tA = make_float4(0.f, 0.f, 0.f, 0.f);
  float4 tB = make_float4(0.f, 0.f, 0.f, 0.f);
#pragma unroll 4
  for (int i = 0; i < A; ++i) {
    float4 e = *(const float4*)(ekb + (size_t)i * TV);
    float av = attn_v[i];
    float qa = eqA[i];
    float qb = eqB[i];
    tA.x += av * __builtin_amdgcn_rcpf(fmaf(e.x, qa, 1.f));
    tA.y += av * __builtin_amdgcn_rcpf(fmaf(e.y, qa, 1.f));
    tA.z += av * __builtin_amdgcn_rcpf(fmaf(e.z, qa, 1.f));
    tA.w += av * __builtin_amdgcn_rcpf(fmaf(e.w, qa, 1.f));
    tB.x += av * __builtin_amdgcn_rcpf(fmaf(e.x, qb, 1.f));
    tB.y += av * __builtin_amdgcn_rcpf(fmaf(e.y, qb, 1.f));
    tB.z += av * __builtin_amdgcn_rcpf(fmaf(e.z, qb, 1.f));
    tB.w += av * __builtin_amdgcn_rcpf(fmaf(e.w, qb, 1.f));
  }
  int4 mk = *(const int4*)(mask + b * TV + v0);
  float4 sA, sB;
  sA.x = sumV - 2.f * tA.x + (1.f - (float)mk.x) * NEG_BIG_F;
  sA.y = sumV - 2.f * tA.y + (1.f - (float)mk.y) * NEG_BIG_F;
  sA.z = sumV - 2.f * tA.z + (1.f - (float)mk.z) * NEG_BIG_F;
  sA.w = sumV - 2.f * tA.w + (1.f - (float)mk.w) * NEG_BIG_F;
  sB.x = sumV - 2.f * tB.x + (1.f - (float)mk.x) * NEG_BIG_F;
  sB.y = sumV - 2.f * tB.y + (1.f - (float)mk.y) * NEG_BIG_F;
  sB.z = sumV - 2.f * tB.z + (1.f - (float)mk.z) * NEG_BIG_F;
  sB.w = sumV - 2.f * tB.w + (1.f - (float)mk.w) * NEG_BIG_F;

  float mA = fmaxf(fmaxf(sA.x, sA.y), fmaxf(sA.z, sA.w));
  float mB = fmaxf(fmaxf(sB.x, sB.y), fmaxf(sB.z, sB.w));
  for (int off = 32; off > 0; off >>= 1) {
    mA = fmaxf(mA, __shfl_down(mA, off, 64));
    mB = fmaxf(mB, __shfl_down(mB, off, 64));
  }
  int w = tid >> 6;
  if ((tid & 63) == 0) { redA[w] = mA; redB[w] = mB; }
  __syncthreads();
  if (tid == 0) {
    bc[0] = fmaxf(fmaxf(redA[0], redA[1]), fmaxf(redA[2], redA[3]));
    bc[1] = fmaxf(fmaxf(redB[0], redB[1]), fmaxf(redB[2], redB[3]));
  }
  __syncthreads();
  float MA = bc[0], MB = bc[1];

  float4 eAv, eBv;
  eAv.x = __builtin_amdgcn_exp2f((sA.x - MA) * LOG2E);
  eAv.y = __builtin_amdgcn_exp2f((sA.y - MA) * LOG2E);
  eAv.z = __builtin_amdgcn_exp2f((sA.z - MA) * LOG2E);
  eAv.w = __builtin_amdgcn_exp2f((sA.w - MA) * LOG2E);
  eBv.x = __builtin_amdgcn_exp2f((sB.x - MB) * LOG2E);
  eBv.y = __builtin_amdgcn_exp2f((sB.y - MB) * LOG2E);
  eBv.z = __builtin_amdgcn_exp2f((sB.z - MB) * LOG2E);
  eBv.w = __builtin_amdgcn_exp2f((sB.w - MB) * LOG2E);
  float lA = (eAv.x + eAv.y) + (eAv.z + eAv.w);
  float lB = (eBv.x + eBv.y) + (eBv.z + eBv.w);
  for (int off = 32; off > 0; off >>= 1) {
    lA += __shfl_down(lA, off, 64);
    lB += __shfl_down(lB, off, 64);
  }
  __syncthreads();   // protect red[] before rewrite
  if ((tid & 63) == 0) { redA[w] = lA; redB[w] = lB; }
  __syncthreads();
  if (tid == 0) {
    bc[2] = (redA[0] + redA[1]) + (redA[2] + redA[3]);
    bc[3] = (redB[0] + redB[1]) + (redB[2] + redB[3]);
  }
  __syncthreads();
  float iA = 1.f / bc[2];
  float iB = 1.f / bc[3];

  float4 oA = make_float4(eAv.x * iA, eAv.y * iA, eAv.z * iA, eAv.w * iA);
  float4 oB = make_float4(eBv.x * iB, eBv.y * iB, eBv.z * iB, eBv.w * iB);
  *(float4*)(attn + (size_t)r0 * TV + v0)       = oA;
  *(float4*)(attn + (size_t)(r0 + 1) * TV + v0) = oB;
}

// ---------------------------------------------------------------------------
// out[b,q,:] += sum_{v-chunk} attn[b,q,v] * inputs[b,v,:]
// Block = 512 thr (8 waves). Wave = one q-group of 8 rows (attn LDS reads are
// wave-uniform -> broadcast). Lanes span 64 float4 d-cols = 256 d: X loads
// fully deduplicated (1KB unique/instr). Register tile 8q x 4d = 32 acc;
// 128 FMA per 4 X loads. Explicit double-buffered X prefetch.
// grid (dt2*vs8, qt4, b4) = 256 blocks. Atomic partials (out pre-zeroed).
// ---------------------------------------------------------------------------
__global__ __launch_bounds__(512, 4) void pv_kernel(
    const float* __restrict__ attn, const float* __restrict__ X,
    float* __restrict__ out) {
  __shared__ float at[64][128];   // 32 KB attn tile (q, v-chunk)
  int b  = blockIdx.z;
  int qt = blockIdx.y;            // 4 tiles of 64 q
  int dt = blockIdx.x & 1;        // 2 d-slices of 256
  int vs = blockIdx.x >> 1;       // 8 v-chunks of 128
  int tid  = threadIdx.x;
  int dcol = tid & 63;            // 64 float4 cols = 256 d
  int qg   = tid >> 6;            // wave id 0..7, 8 q-rows each
  int d0 = dt * 256 + dcol * 4;
  int q0 = qt * 64;
  int vbase = vs * 128;

  // stage attn tile: 64 q x 128 v (float4, coalesced)
  for (int i = tid; i < 64 * 32; i += 512) {
    int row = i >> 5, c4 = i & 31;
    ((float4*)&at[row][0])[c4] =
        *(const float4*)(attn + (size_t)(b * TQ + q0 + row) * TV + vbase + c4 * 4);
  }
  __syncthreads();

  float4 acc[8];
#pragma unroll
  for (int j = 0; j < 8; ++j) acc[j] = make_float4(0.f, 0.f, 0.f, 0.f);

  const float* Xb = X + ((size_t)b * TV + vbase) * D + d0;
  float4 xc0 = *(const float4*)(Xb + (size_t)0 * D);
  float4 xc1 = *(const float4*)(Xb + (size_t)1 * D);
  float4 xc2 = *(const float4*)(Xb + (size_t)2 * D);
  float4 xc3 = *(const float4*)(Xb + (size_t)3 * D);

#pragma unroll 2
  for (int vi = 0; vi < 124; vi += 4) {
    const float* Xn = Xb + (size_t)(vi + 4) * D;
    float4 xn0 = *(const float4*)(Xn + (size_t)0 * D);
    float4 xn1 = *(const float4*)(Xn + (size_t)1 * D);
    float4 xn2 = *(const float4*)(Xn + (size_t)2 * D);
    float4 xn3 = *(const float4*)(Xn + (size_t)3 * D);
#pragma unroll
    for (int j = 0; j < 8; ++j) {
      float4 av = *(const float4*)&at[qg * 8 + j][vi];  // wave-uniform bcast
      acc[j].x = fmaf(av.x, xc0.x, acc[j].x);
      acc[j].y = fmaf(av.x, xc0.y, acc[j].y);
      acc[j].z = fmaf(av.x, xc0.z, acc[j].z);
      acc[j].w = fmaf(av.x, xc0.w, acc[j].w);
      acc[j].x = fmaf(av.y, xc1.x, acc[j].x);
      acc[j].y = fmaf(av.y, xc1.y, acc[j].y);
      acc[j].z = fmaf(av.y, xc1.z, acc[j].z);
      acc[j].w = fmaf(av.y, xc1.w, acc[j].w);
      acc[j].x = fmaf(av.z, xc2.x, acc[j].x);
      acc[j].y = fmaf(av.z, xc2.y, acc[j].y);
      acc[j].z = fmaf(av.z, xc2.z, acc[j].z);
      acc[j].w = fmaf(av.z, xc2.w, acc[j].w);
      acc[j].x = fmaf(av.w, xc3.x, acc[j].x);
      acc[j].y = fmaf(av.w, xc3.y, acc[j].y);
      acc[j].z = fmaf(av.w, xc3.z, acc[j].z);
      acc[j].w = fmaf(av.w, xc3.w, acc[j].w);
    }
    xc0 = xn0; xc1 = xn1; xc2 = xn2; xc3 = xn3;
  }
  // last unit (vi = 124)
#pragma unroll
  for (int j = 0; j < 8; ++j) {
    float4 av = *(const float4*)&at[qg * 8 + j][124];
    acc[j].x = fmaf(av.x, xc0.x, acc[j].x);
    acc[j].y = fmaf(av.x, xc0.y, acc[j].y);
    acc[j].z = fmaf(av.x, xc0.z, acc[j].z);
    acc[j].w = fmaf(av.x, xc0.w, acc[j].w);
    acc[j].x = fmaf(av.y, xc1.x, acc[j].x);
    acc[j].y = fmaf(av.y, xc1.y, acc[j].y);
    acc[j].z = fmaf(av.y, xc1.z, acc[j].z);
    acc[j].w = fmaf(av.y, xc1.w, acc[j].w);
    acc[j].x = fmaf(av.z, xc2.x, acc[j].x);
    acc[j].y = fmaf(av.z, xc2.y, acc[j].y);
    acc[j].z = fmaf(av.z, xc2.z, acc[j].z);
    acc[j].w = fmaf(av.z, xc2.w, acc[j].w);
    acc[j].x = fmaf(av.w, xc3.x, acc[j].x);
    acc[j].y = fmaf(av.w, xc3.y, acc[j].y);
    acc[j].z = fmaf(av.w, xc3.z, acc[j].z);
    acc[j].w = fmaf(av.w, xc3.w, acc[j].w);
  }

#pragma unroll
  for (int j = 0; j < 8; ++j) {
    float* o = out + (size_t)(b * TQ + q0 + qg * 8 + j) * D + d0;
    unsafeAtomicAdd(o + 0, acc[j].x);
    unsafeAtomicAdd(o + 1, acc[j].y);
    unsafeAtomicAdd(o + 2, acc[j].z);
    unsafeAtomicAdd(o + 3, acc[j].w);
  }
}

extern "C" void kernel_launch(void* const* d_in, const int* in_sizes, int n_in,
                              void* d_out, int out_size, void* d_ws, size_t ws_size,
                              hipStream_t stream) {
  const float* inputs  = (const float*)d_in[0];  // [B,TV,D]
  const float* context = (const float*)d_in[1];  // [B,TQ,D]
  const int*   mask    = (const int*)d_in[2];    // [B,TV]
  const float* Wk      = (const float*)d_in[3];  // [D,A]
  const float* bk      = (const float*)d_in[4];  // [A]
  const float* Wq      = (const float*)d_in[5];  // [D,A]
  const float* bq      = (const float*)d_in[6];  // [A]
  const float* attn_v  = (const float*)d_in[7];  // [A]
  float* out = (float*)d_out;                    // [B,TQ,D]

  // Workspace layout (fp32): Eq | EkT | attn  = 0.5MB + 2MB + 4MB
  float* Eq   = (float*)d_ws;             // [B*TQ, A]
  float* EkT  = Eq + B * TQ * A;          // [B, A, TV]  (transposed!)
  float* attn = EkT + (size_t)B * A * TV; // [B*TQ, TV]

  proj_exp_kernel<<<QBLK + KBLK, 512, 0, stream>>>(context, inputs, Wq, bq,
                                                   Wk, bk, Eq, EkT, out);
  score_softmax_kernel<<<B * TQ / 2, 256, 0, stream>>>(Eq, EkT, attn_v, mask,
                                                       attn);
  pv_kernel<<<dim3(16, 4, 4), 512, 0, stream>>>(attn, inputs, out);
}

// Round 6
// 145.300 us; speedup vs baseline: 1.2918x; 1.2918x over previous
//
#include <hip/hip_runtime.h>
#include <math.h>

// Problem sizes (fixed by the reference)
#define B   4
#define TQ  256
#define TV  1024
#define D   512
#define A   128

#define LOG2E     1.4426950408889634f
#define TWO_LOG2E 2.8853900817779268f
#define NEG_BIG_F (-1e9f)

#define QBLK (B * TQ / 8)   // 128 q-projection blocks
#define KBLK (B * TV / 8)   // 512 k-projection blocks

// ---------------------------------------------------------------------------
// Fused projection + exp(2x) for BOTH q and k.
//   q path: Eq[r, a]     = exp(2*(ctx[r,:]@Wq[:,a] + bq[a]))   [row-major]
//   k path: EkT[b, a, v] = exp(2*(inp[r,:]@Wk[:,a] + bk[a]))   [TRANSPOSED]
// ---------------------------------------------------------------------------
__global__ __launch_bounds__(512) void proj_exp_kernel(
    const float* __restrict__ ctx, const float* __restrict__ inp,
    const float* __restrict__ Wq, const float* __restrict__ bq,
    const float* __restrict__ Wk, const float* __restrict__ bk,
    float* __restrict__ Eq, float* __restrict__ EkT) {
  __shared__ float xs[8][D];        // 16 KB
  __shared__ float ps[8][4][A];     // 16 KB (row j, quarter, a)
  __shared__ float es[A][9];        // 4.6 KB (transpose staging, +1 pad)

  bool isQ = blockIdx.x < QBLK;
  const float* X; const float* W; const float* bias; int r0;
  if (isQ) { X = ctx; W = Wq; bias = bq; r0 = blockIdx.x * 8; }
  else     { X = inp; W = Wk; bias = bk; r0 = (blockIdx.x - QBLK) * 8; }

  // stage 8 rows of X (float4, coalesced)
  {
    const float4* Xv = (const float4*)(X + (size_t)r0 * D);
    float4* xsv = (float4*)&xs[0][0];
    for (int i = threadIdx.x; i < 8 * D / 4; i += 512) xsv[i] = Xv[i];
  }
  __syncthreads();

  int a = threadIdx.x & 127;
  int h = threadIdx.x >> 7;        // 0..3, splits d-range into quarters
  float acc[8];
#pragma unroll
  for (int j = 0; j < 8; ++j) acc[j] = 0.f;

  int dbase = h * (D / 4);
#pragma unroll 2
  for (int dd = 0; dd < D / 4; dd += 4) {
    int d = dbase + dd;
    float w0 = W[(d + 0) * A + a];
    float w1 = W[(d + 1) * A + a];
    float w2 = W[(d + 2) * A + a];
    float w3 = W[(d + 3) * A + a];
#pragma unroll
    for (int j = 0; j < 8; ++j) {
      float4 x = *(const float4*)&xs[j][d];   // wave-uniform addr -> broadcast
      acc[j] = fmaf(x.x, w0, acc[j]);
      acc[j] = fmaf(x.y, w1, acc[j]);
      acc[j] = fmaf(x.z, w2, acc[j]);
      acc[j] = fmaf(x.w, w3, acc[j]);
    }
  }
#pragma unroll
  for (int j = 0; j < 8; ++j) ps[j][h][a] = acc[j];
  __syncthreads();

  float bz = bias[a];
  if (isQ) {
#pragma unroll
    for (int j = h * 2; j < h * 2 + 2; ++j) {
      float t = ((ps[j][0][a] + ps[j][1][a]) + (ps[j][2][a] + ps[j][3][a])) + bz;
      Eq[(size_t)(r0 + j) * A + a] = __builtin_amdgcn_exp2f(t * TWO_LOG2E);
    }
  } else {
#pragma unroll
    for (int j = h * 2; j < h * 2 + 2; ++j) {
      float t = ((ps[j][0][a] + ps[j][1][a]) + (ps[j][2][a] + ps[j][3][a])) + bz;
      es[a][j] = __builtin_amdgcn_exp2f(t * TWO_LOG2E);
    }
    __syncthreads();
    int b  = r0 >> 10;          // TV == 1024
    int v0 = r0 & (TV - 1);
    for (int i = threadIdx.x; i < A * 8; i += 512) {
      int aa = i >> 3, jj = i & 7;
      EkT[((size_t)b * A + aa) * TV + v0 + jj] = es[aa][jj];
    }
  }
}

// ---------------------------------------------------------------------------
// Scores + softmax: FOUR q rows per block, 256 threads (4 waves). Thread owns
// 4 consecutive v; each EkT float4 load feeds 16 independent rcp chains
// (4 rows x 4 v) -> trans pipe stays fed even at low occupancy.
// 256 blocks. Explicit next-load prefetch.
//   score[v] = sumV - 2 * sum_a v_a / (Eq[a]*EkT[a,v] + 1)
// ---------------------------------------------------------------------------
__global__ __launch_bounds__(256, 4) void score_softmax_kernel(
    const float* __restrict__ Eq, const float* __restrict__ EkT,
    const float* __restrict__ attn_v, const int* __restrict__ mask,
    float* __restrict__ attn) {
  __shared__ float red[4][4];  // [row][wave]
  __shared__ float bc[8];

  int tid = threadIdx.x;
  int v0  = (tid & 63) * 4 + (tid >> 6) * 256;  // wave-contiguous float4
  int r0  = blockIdx.x * 4;
  int b   = r0 >> 8;               // TQ == 256

  const float* eqA = Eq + (size_t)r0 * A;
  const float* eqB = eqA + A;
  const float* eqC = eqB + A;
  const float* eqD = eqC + A;

  float sumV = 0.f;
#pragma unroll 16
  for (int i = 0; i < A; ++i) sumV += attn_v[i];

  const float* ekb = EkT + (size_t)b * A * TV + v0;
  float4 tA = make_float4(0.f, 0.f, 0.f, 0.f);
  float4 tB = tA, tC = tA, tD = tA;

  float4 e = *(const float4*)(ekb);
#pragma unroll 4
  for (int i = 0; i < A; ++i) {
    float4 en;
    if (i < A - 1) en = *(const float4*)(ekb + (size_t)(i + 1) * TV);
    float av = attn_v[i];
    float qa = eqA[i], qb = eqB[i], qc = eqC[i], qd = eqD[i];
    tA.x += av * __builtin_amdgcn_rcpf(fmaf(e.x, qa, 1.f));
    tA.y += av * __builtin_amdgcn_rcpf(fmaf(e.y, qa, 1.f));
    tA.z += av * __builtin_amdgcn_rcpf(fmaf(e.z, qa, 1.f));
    tA.w += av * __builtin_amdgcn_rcpf(fmaf(e.w, qa, 1.f));
    tB.x += av * __builtin_amdgcn_rcpf(fmaf(e.x, qb, 1.f));
    tB.y += av * __builtin_amdgcn_rcpf(fmaf(e.y, qb, 1.f));
    tB.z += av * __builtin_amdgcn_rcpf(fmaf(e.z, qb, 1.f));
    tB.w += av * __builtin_amdgcn_rcpf(fmaf(e.w, qb, 1.f));
    tC.x += av * __builtin_amdgcn_rcpf(fmaf(e.x, qc, 1.f));
    tC.y += av * __builtin_amdgcn_rcpf(fmaf(e.y, qc, 1.f));
    tC.z += av * __builtin_amdgcn_rcpf(fmaf(e.z, qc, 1.f));
    tC.w += av * __builtin_amdgcn_rcpf(fmaf(e.w, qc, 1.f));
    tD.x += av * __builtin_amdgcn_rcpf(fmaf(e.x, qd, 1.f));
    tD.y += av * __builtin_amdgcn_rcpf(fmaf(e.y, qd, 1.f));
    tD.z += av * __builtin_amdgcn_rcpf(fmaf(e.z, qd, 1.f));
    tD.w += av * __builtin_amdgcn_rcpf(fmaf(e.w, qd, 1.f));
    e = en;
  }

  int4 mk = *(const int4*)(mask + b * TV + v0);
  float4 mks;
  mks.x = (1.f - (float)mk.x) * NEG_BIG_F;
  mks.y = (1.f - (float)mk.y) * NEG_BIG_F;
  mks.z = (1.f - (float)mk.z) * NEG_BIG_F;
  mks.w = (1.f - (float)mk.w) * NEG_BIG_F;

  float4 s[4];
  s[0] = make_float4(sumV - 2.f * tA.x + mks.x, sumV - 2.f * tA.y + mks.y,
                     sumV - 2.f * tA.z + mks.z, sumV - 2.f * tA.w + mks.w);
  s[1] = make_float4(sumV - 2.f * tB.x + mks.x, sumV - 2.f * tB.y + mks.y,
                     sumV - 2.f * tB.z + mks.z, sumV - 2.f * tB.w + mks.w);
  s[2] = make_float4(sumV - 2.f * tC.x + mks.x, sumV - 2.f * tC.y + mks.y,
                     sumV - 2.f * tC.z + mks.z, sumV - 2.f * tC.w + mks.w);
  s[3] = make_float4(sumV - 2.f * tD.x + mks.x, sumV - 2.f * tD.y + mks.y,
                     sumV - 2.f * tD.z + mks.z, sumV - 2.f * tD.w + mks.w);

  int w = tid >> 6;
  float mx[4];
#pragma unroll
  for (int r = 0; r < 4; ++r) {
    float m = fmaxf(fmaxf(s[r].x, s[r].y), fmaxf(s[r].z, s[r].w));
    for (int off = 32; off > 0; off >>= 1)
      m = fmaxf(m, __shfl_down(m, off, 64));
    if ((tid & 63) == 0) red[r][w] = m;
  }
  __syncthreads();
  if (tid < 4)
    bc[tid] = fmaxf(fmaxf(red[tid][0], red[tid][1]),
                    fmaxf(red[tid][2], red[tid][3]));
  __syncthreads();

  float4 ex[4];
  float ls[4];
#pragma unroll
  for (int r = 0; r < 4; ++r) {
    float m = bc[r];
    ex[r].x = __builtin_amdgcn_exp2f((s[r].x - m) * LOG2E);
    ex[r].y = __builtin_amdgcn_exp2f((s[r].y - m) * LOG2E);
    ex[r].z = __builtin_amdgcn_exp2f((s[r].z - m) * LOG2E);
    ex[r].w = __builtin_amdgcn_exp2f((s[r].w - m) * LOG2E);
    ls[r] = (ex[r].x + ex[r].y) + (ex[r].z + ex[r].w);
    for (int off = 32; off > 0; off >>= 1)
      ls[r] += __shfl_down(ls[r], off, 64);
  }
  __syncthreads();   // red[] reuse
#pragma unroll
  for (int r = 0; r < 4; ++r)
    if ((tid & 63) == 0) red[r][w] = ls[r];
  __syncthreads();
  if (tid < 4)
    bc[4 + tid] = (red[tid][0] + red[tid][1]) + (red[tid][2] + red[tid][3]);
  __syncthreads();

#pragma unroll
  for (int r = 0; r < 4; ++r) {
    float inv = 1.f / bc[4 + r];
    float4 o = make_float4(ex[r].x * inv, ex[r].y * inv,
                           ex[r].z * inv, ex[r].w * inv);
    *(float4*)(attn + (size_t)(r0 + r) * TV + v0) = o;
  }
}

// ---------------------------------------------------------------------------
// out[b,q,:] = sum_v attn[b,q,v] * inputs[b,v,:]   -- NO ATOMICS.
// Block tile: 16 q x 128 d over the FULL v range; the v-sum is split across
// the 8 waves (each owns a disjoint 128-v chunk -> no duplicated X traffic),
// wave partials reduced through LDS (reusing the attn-tile buffer), single
// plain coalesced store. grid (dt=4, qtile=64) = 256 blocks x 512 thr.
// Wave layout: lane = (qh<<5)|col; col 0..31 -> float4 d-col; qh -> 8-q half.
// Register tile 8q x 4d = 32 acc; 32 FMA per X float4 load.
// ---------------------------------------------------------------------------
__global__ __launch_bounds__(512, 4) void pv_kernel(
    const float* __restrict__ attn, const float* __restrict__ X,
    float* __restrict__ out) {
  __shared__ float lds[16 * 1024];   // 64 KB: attn tile, then 8 partial tiles
  int dt = blockIdx.x;               // 0..3, d-slice of 128
  int q0 = blockIdx.y * 16;          // global row (b*TQ + q), 64 tiles
  int b  = q0 >> 8;                  // TQ == 256
  int tid  = threadIdx.x;
  int w    = tid >> 6;               // wave 0..7 -> v range [w*128, w*128+128)
  int lane = tid & 63;
  int col  = lane & 31;              // float4 d-column
  int qh   = lane >> 5;              // 0..1 -> q rows qh*8 .. qh*8+7
  int d0 = dt * 128 + col * 4;

  // stage attn tile: 16 rows x 1024 v (float4, coalesced)
  {
    const float4* src = (const float4*)(attn + (size_t)q0 * TV);
    float4* dst = (float4*)lds;
    for (int i = tid; i < 16 * 256; i += 512) dst[i] = src[i];
  }
  __syncthreads();

  float4 acc[8];
#pragma unroll
  for (int j = 0; j < 8; ++j) acc[j] = make_float4(0.f, 0.f, 0.f, 0.f);

  int vbase = w * 128;
  const float* Xb = X + ((size_t)b * TV + vbase) * D + d0;
  const float* arow = &lds[(qh * 8) * 1024 + vbase];  // 8 rows, stride 1024

  float4 xc0 = *(const float4*)(Xb + (size_t)0 * D);
  float4 xc1 = *(const float4*)(Xb + (size_t)1 * D);
  float4 xc2 = *(const float4*)(Xb + (size_t)2 * D);
  float4 xc3 = *(const float4*)(Xb + (size_t)3 * D);

  for (int vi = 0; vi < 128; vi += 4) {
    float4 xn0, xn1, xn2, xn3;
    if (vi < 124) {
      const float* Xn = Xb + (size_t)(vi + 4) * D;
      xn0 = *(const float4*)(Xn + (size_t)0 * D);
      xn1 = *(const float4*)(Xn + (size_t)1 * D);
      xn2 = *(const float4*)(Xn + (size_t)2 * D);
      xn3 = *(const float4*)(Xn + (size_t)3 * D);
    }
#pragma unroll
    for (int j = 0; j < 8; ++j) {
      float4 av = *(const float4*)(arow + j * 1024 + vi);  // 2-addr bcast
      acc[j].x = fmaf(av.x, xc0.x, acc[j].x);
      acc[j].y = fmaf(av.x, xc0.y, acc[j].y);
      acc[j].z = fmaf(av.x, xc0.z, acc[j].z);
      acc[j].w = fmaf(av.x, xc0.w, acc[j].w);
      acc[j].x = fmaf(av.y, xc1.x, acc[j].x);
      acc[j].y = fmaf(av.y, xc1.y, acc[j].y);
      acc[j].z = fmaf(av.y, xc1.z, acc[j].z);
      acc[j].w = fmaf(av.y, xc1.w, acc[j].w);
      acc[j].x = fmaf(av.z, xc2.x, acc[j].x);
      acc[j].y = fmaf(av.z, xc2.y, acc[j].y);
      acc[j].z = fmaf(av.z, xc2.z, acc[j].z);
      acc[j].w = fmaf(av.z, xc2.w, acc[j].w);
      acc[j].x = fmaf(av.w, xc3.x, acc[j].x);
      acc[j].y = fmaf(av.w, xc3.y, acc[j].y);
      acc[j].z = fmaf(av.w, xc3.z, acc[j].z);
      acc[j].w = fmaf(av.w, xc3.w, acc[j].w);
    }
    xc0 = xn0; xc1 = xn1; xc2 = xn2; xc3 = xn3;
  }

  __syncthreads();   // everyone done READING the attn tile

  // write wave partials: lds[w][16 rows][32 float4 cols]
  {
    float4* pat = (float4*)lds + (size_t)w * 512;
#pragma unroll
    for (int j = 0; j < 8; ++j)
      pat[(qh * 8 + j) * 32 + col] = acc[j];
  }
  __syncthreads();

  // reduce 8 partials and store: 512 float4 outputs, one per thread
  {
    int row = tid >> 5;            // 0..15
    int c   = tid & 31;            // 0..31
    const float4* p = (const float4*)lds + tid;  // == row*32 + c
    float4 r = p[0];
#pragma unroll
    for (int i = 1; i < 8; ++i) {
      float4 t = p[(size_t)i * 512];
      r.x += t.x; r.y += t.y; r.z += t.z; r.w += t.w;
    }
    *(float4*)(out + (size_t)(q0 + row) * D + dt * 128 + c * 4) = r;
  }
}

extern "C" void kernel_launch(void* const* d_in, const int* in_sizes, int n_in,
                              void* d_out, int out_size, void* d_ws, size_t ws_size,
                              hipStream_t stream) {
  const float* inputs  = (const float*)d_in[0];  // [B,TV,D]
  const float* context = (const float*)d_in[1];  // [B,TQ,D]
  const int*   mask    = (const int*)d_in[2];    // [B,TV]
  const float* Wk      = (const float*)d_in[3];  // [D,A]
  const float* bk      = (const float*)d_in[4];  // [A]
  const float* Wq      = (const float*)d_in[5];  // [D,A]
  const float* bq      = (const float*)d_in[6];  // [A]
  const float* attn_v  = (const float*)d_in[7];  // [A]
  float* out = (float*)d_out;                    // [B,TQ,D]

  // Workspace layout (fp32): Eq | EkT | attn  = 0.5MB + 2MB + 4MB
  float* Eq   = (float*)d_ws;             // [B*TQ, A]
  float* EkT  = Eq + B * TQ * A;          // [B, A, TV]  (transposed!)
  float* attn = EkT + (size_t)B * A * TV; // [B*TQ, TV]

  proj_exp_kernel<<<QBLK + KBLK, 512, 0, stream>>>(context, inputs, Wq, bq,
                                                   Wk, bk, Eq, EkT);
  score_softmax_kernel<<<B * TQ / 4, 256, 0, stream>>>(Eq, EkT, attn_v, mask,
                                                       attn);
  pv_kernel<<<dim3(4, 64), 512, 0, stream>>>(attn, inputs, out);
}